// Round 14
// baseline (211.903 us; speedup 1.0000x reference)
//
#include <hip/hip_runtime.h>

// ---------------------------------------------------------------------------
// NearestSim: out[t] = -cos(q_t, items[argmax_j q_t . items_j])
// T=16384, M=4096, C=512, fp32 in/out.
// R25 = R24 (128q-per-wave, 2-phase staging, depth-2 B, med3/ds_swizzle
//       epilogue — best: 81.6us score / 168.6us total) + convert-Q fusion:
//  - score stages Q by reg-staging: fp32 global_load x2 -> cvt (RNE, same
//    numerics as convert) -> ds_write_b128, replacing global_load_lds from
//    the pre-converted fp16 image. convert shrinks to items-only (~3us,
//    was ~12). Q fp32 re-reads stay L2-resident (XCD = qtile%8).
//  - staging completion now tracked by lgkmcnt -> ALL barriers are
//    "s_waitcnt lgkmcnt(0); s_barrier": vmcnt never drains, so k8/k9 B
//    prefetches survive the mid-kernel barrier pair (R24 drained them).
//  - Rationale: 11 structural score experiments moved MfmaUtil 35% by <4%
//    (distributed-latency plateau); total-minus-score ~85us is now the
//    better marginal target. K-loop/epilogue/rescue unchanged.
// ---------------------------------------------------------------------------

#define TQ 16384
#define MI 4096
#define CD 512
#define NIS 16          // item splits; block covers 256 items
#define BM 128          // block query rows (= wave q-rows)

typedef _Float16 half8   __attribute__((ext_vector_type(8)));
typedef _Float16 half4_t __attribute__((ext_vector_type(4)));
typedef float    float4t __attribute__((ext_vector_type(4)));

// workspace layout (bytes) — QH region retained but unused (offsets stable)
#define QH_OFF   (0u)
#define QH_BYTES ((unsigned)TQ * CD * 2u)
#define IH_OFF   (QH_OFF + QH_BYTES)
#define IH_BYTES ((unsigned)MI * CD * 2u)          // 4 MB fp16 items (fragment order)
#define PART_OFF (IH_OFF + IH_BYTES)
#define PART_BYTES ((unsigned)TQ * 64u * 8u)       // 8 MB: 64 float2 / query

template <int SWZ>
__device__ __forceinline__ float swz_f(float x) {
  return __int_as_float(__builtin_amdgcn_ds_swizzle(__float_as_int(x), SWZ));
}

// ---------------- kernel 1: items fp32 -> fp16 fragment image ---------------
// chunk ic = (tile16*16+kk)*64 + lane; lane = quad*16+l15 holds row
// tile16*16+l15, cols kk*32+quad*8..+8.
__global__ __launch_bounds__(256) void convert_kernel(
    const float* __restrict__ it, char* __restrict__ ws) {
  const int ic = blockIdx.x * 256 + threadIdx.x;
  const int IC = MI * CD / 8;
  if (ic < IC) {
    const int tile = ic >> 10;
    const int rem  = ic & 1023;
    const int kk   = rem >> 6;
    const int lane = rem & 63;
    const int row  = tile * 16 + (lane & 15);
    const int col  = kk * 32 + (lane >> 4) * 8;
    const float4* s = (const float4*)(it + (size_t)row * CD + col);
    float4 v0 = s[0], v1 = s[1];
    half8 h = {(_Float16)v0.x, (_Float16)v0.y, (_Float16)v0.z, (_Float16)v0.w,
               (_Float16)v1.x, (_Float16)v1.y, (_Float16)v1.z, (_Float16)v1.w};
    *(half8*)(ws + IH_OFF + (size_t)ic * 16) = h;
  }
}

// ---------------- kernel 2: 128q-per-wave fused GEMM + packed top-2 ---------
// grid (TQ/128, NIS), block 256 = 4 waves; wave tile 128q x 64i (8x4 MFMAs
// of 16x16x32, 128 acc). A image: 2 phases of K=256, 128 rows x 512B = 64KB,
// REG-STAGED from fp32 q (load x2 -> cvt -> ds_write_b128).
// B direct global (fp16 item image), depth-2 rotation, 4 loads/kstep.
// LDS image (per phase): row r (0..127) at r*512; 32 chunks of 16B;
// phys chunk = logical c ^ (r&15)  -> a-frag b128 reads conflict-free.
// Staging map: unit j (0..15), thread t -> dest = j*4096 + t*16;
//   row = j*8 + (t>>5), phys chunk = t&31,
//   logical c = (t&31) ^ (t>>5) ^ (8*(j&1)).
//   fp32 source: q + (qtile*128 + row)*512 + phase*256 + c*8   (floats)
__global__ __launch_bounds__(256, 2) void score_kernel(
    const float* __restrict__ q, char* __restrict__ ws) {
  __shared__ __align__(16) char sA[65536];  // 64 KB, re-staged per phase

  const int tid  = threadIdx.x;
  const int lane = tid & 63;
  const int wave = tid >> 6;       // 0..3 (item group)
  const int quad = lane >> 4;
  const int l15  = lane & 15;
  const int qtile = blockIdx.x;    // 0..127; XCD = qtile%8
  const int isplit = blockIdx.y;

  // staging sources (floats): even j rows 16m+u, odd j rows 16m+8+u
  const int u  = tid >> 5;         // 0..7
  const int p5 = tid & 31;
  const float* gq0 = q + ((size_t)qtile * 128 + u) * 512 + (p5 ^ u) * 8;
  const float* gq1 = q + ((size_t)qtile * 128 + 8 + u) * 512 + ((p5 ^ u) ^ 8) * 8;
  const int ldst = tid * 16;  // + j*4096

  // B stream: tile(ni) = isplit*16 + wave*4 + ni
  const char* Ibase = ws + IH_OFF;
  int bOff[4];
#pragma unroll
  for (int ni = 0; ni < 4; ++ni)
    bOff[ni] = ((isplit * 16 + wave * 4 + ni) << 14) + lane * 16;

  // A fragment: byte = mi*8192 + l15*512 + (((kl*4+quad) ^ l15) << 4)
  const int aRow = l15 * 512;

  float4t acc[8][4];
#pragma unroll
  for (int mi = 0; mi < 8; ++mi)
#pragma unroll
    for (int ni = 0; ni < 4; ++ni) acc[mi][ni] = (float4t){0.f, 0.f, 0.f, 0.f};

  half8 aC[8], bC[4], bN[4], bN2[4];

#define STAGE(ph)                                                         \
  {                                                                       \
    _Pragma("unroll") for (int m = 0; m < 8; ++m) {                       \
      const float4* s0 = (const float4*)(gq0 + m * 8192 + (ph) * 256);    \
      float4 v0 = s0[0], v1 = s0[1];                                      \
      half8 h0 = {(_Float16)v0.x, (_Float16)v0.y, (_Float16)v0.z,         \
                  (_Float16)v0.w, (_Float16)v1.x, (_Float16)v1.y,         \
                  (_Float16)v1.z, (_Float16)v1.w};                        \
      *(half8*)(sA + (2 * m) * 4096 + ldst) = h0;                         \
      const float4* s1 = (const float4*)(gq1 + m * 8192 + (ph) * 256);    \
      float4 w0 = s1[0], w1 = s1[1];                                      \
      half8 h1 = {(_Float16)w0.x, (_Float16)w0.y, (_Float16)w0.z,         \
                  (_Float16)w0.w, (_Float16)w1.x, (_Float16)w1.y,         \
                  (_Float16)w1.z, (_Float16)w1.w};                        \
      *(half8*)(sA + (2 * m + 1) * 4096 + ldst) = h1;                     \
    }                                                                     \
  }

  // staged-image barrier: drains this wave's ds_writes (lgkmcnt) only;
  // global-load queue (B prefetches) stays in flight across it.
#define LBAR() asm volatile("s_waitcnt lgkmcnt(0)\n\ts_barrier" ::: "memory")

  STAGE(0);

  // B prologue: k0 -> bC, k1 -> bN (8 loads, stay in flight across LBAR)
#pragma unroll
  for (int ni = 0; ni < 4; ++ni) bC[ni] = *(const half8*)(Ibase + bOff[ni]);
#pragma unroll
  for (int ni = 0; ni < 4; ++ni)
    bN[ni] = *(const half8*)(Ibase + bOff[ni] + 1024);

  LBAR();            // phase-0 image visible; B loads untouched

#define KPHASE(ph)                                                        \
  {                                                                       \
    _Pragma("unroll") for (int kl = 0; kl < 8; ++kl) {                    \
      const int kkg = (ph) * 8 + kl;                                      \
      if (kkg + 2 < 16) {  /* depth-2 B prefetch */                       \
        _Pragma("unroll") for (int ni = 0; ni < 4; ++ni)                  \
          bN2[ni] = *(const half8*)(Ibase + bOff[ni] + 2048);             \
      }                                                                   \
      {  /* a-frags for this kstep (no prefetch; TLP covers ds latency) */\
        const int c = (((kl << 2) + quad) ^ l15) << 4;                    \
        _Pragma("unroll") for (int mi = 0; mi < 8; ++mi)                  \
          aC[mi] = *(const half8*)(sA + mi * 8192 + aRow + c);            \
      }                                                                   \
      __builtin_amdgcn_s_setprio(1);                                      \
      _Pragma("unroll") for (int mi = 0; mi < 8; ++mi)                    \
        _Pragma("unroll") for (int ni = 0; ni < 4; ++ni)                  \
          acc[mi][ni] = __builtin_amdgcn_mfma_f32_16x16x32_f16(           \
              aC[mi], bC[ni], acc[mi][ni], 0, 0, 0);                      \
      __builtin_amdgcn_s_setprio(0);                                      \
      _Pragma("unroll") for (int x = 0; x < 4; ++x) bC[x] = bN[x];        \
      if (kkg + 2 < 16) {                                                 \
        _Pragma("unroll") for (int x = 0; x < 4; ++x) bN[x] = bN2[x];     \
      }                                                                   \
      _Pragma("unroll") for (int ni = 0; ni < 4; ++ni) bOff[ni] += 1024;  \
    }                                                                     \
  }

  KPHASE(0);
  // all waves done READING phase-0 image (each wave's ds_reads drained by
  // its own MFMA-use waitcnts before arriving) -> safe to overwrite
  asm volatile("s_barrier" ::: "memory");
  STAGE(1);
  LBAR();            // phase-1 image visible; k8/k9 B prefetches survive
  KPHASE(1);

#undef KPHASE
#undef LBAR
#undef STAGE

  // ---- epilogue: packed (score | 12-bit global idx) top-2 per query row ----
  // C row = mi*16 + quad*4 + r, col = l15.
  // item = isplit*256 + wave*64 + ni*16 + l15.
  float t1[32], t2[32];

  const int locBase = isplit * 256 + wave * 64 + l15;
#pragma unroll
  for (int ni = 0; ni < 4; ++ni) {
    const int loc = locBase + ni * 16;
#pragma unroll
    for (int mi = 0; mi < 8; ++mi) {
#pragma unroll
      for (int r = 0; r < 4; ++r) {
        const int s = mi * 4 + r;
        const float pv = __int_as_float(
            (__float_as_int(acc[mi][ni][r]) & 0xFFFFF000) | loc);
        if (ni == 0) {
          t1[s] = pv;
          t2[s] = -1e30f;
        } else {
          t2[s] = __builtin_amdgcn_fmed3f(pv, t1[s], t2[s]);
          t1[s] = fmaxf(t1[s], pv);
        }
      }
    }
  }

  // 4-step butterfly across the 16-lane l15 group via ds_swizzle xor
  // patterns (BitMode: offset = (xor<<10)|0x1F). Disjoint partner sets:
  //   t2' = med3(t1, o1, max(t2, o2)) = max(min(t1,o1), max(t2,o2)).
#define BSTEP(SWZ)                                                       \
  {                                                                      \
    _Pragma("unroll") for (int s = 0; s < 32; ++s) {                     \
      const float o1 = swz_f<SWZ>(t1[s]);                                \
      const float o2 = swz_f<SWZ>(t2[s]);                                \
      t2[s] = __builtin_amdgcn_fmed3f(t1[s], o1, fmaxf(t2[s], o2));      \
      t1[s] = fmaxf(t1[s], o1);                                          \
    }                                                                    \
  }
  BSTEP(0x041F)   // xor 1
  BSTEP(0x081F)   // xor 2
  BSTEP(0x101F)   // xor 4
  BSTEP(0x201F)   // xor 8
#undef BSTEP

  // writer: l15 == 0; entry = isplit*4 + wave. 64 entries per query.
  if (l15 == 0) {
    float2* part = (float2*)(ws + PART_OFF);
    const int e = isplit * 4 + wave;
#pragma unroll
    for (int s = 0; s < 32; ++s) {
      const int qrow = qtile * BM + (s >> 2) * 16 + quad * 4 + (s & 3);
      part[(size_t)qrow * 64 + e] = make_float2(t1[s], t2[s]);
    }
  }
}

// ---------------- kernel 3: merge partials + exact fp32 rescue --------------
// one wave per query: 64 packed entries (1/lane) -> global fp16 top-2.
// If the packed gap exceeds 0.25 (>>5 sigma of fp16+quant score error),
// candidate 1 is certainly the true argmax: skip the 2nd gather entirely
// (wave-uniform branch). Otherwise exact fp32 re-score of both.
__global__ __launch_bounds__(256) void rescue_kernel(
    const float* __restrict__ q, const float* __restrict__ items,
    const char* __restrict__ ws, float* __restrict__ out) {
  const int wave = threadIdx.x >> 6;
  const int lane = threadIdx.x & 63;
  const int qrow = blockIdx.x * 4 + wave;

  const float2* part = (const float2*)(ws + PART_OFF);
  float2 ent = part[(size_t)qrow * 64 + lane];  // coalesced 512B burst
  float t1 = ent.x, t2 = ent.y;

#pragma unroll
  for (int m = 1; m < 64; m <<= 1) {
    const float o1 = __shfl_xor(t1, m, 64);
    const float o2 = __shfl_xor(t2, m, 64);
    const float mn = fminf(t1, o1);
    t1 = fmaxf(t1, o1);
    t2 = fmaxf(fmaxf(t2, o2), mn);
  }
  const int c1i = __float_as_int(t1) & 0xFFF;
  const int c2i = __float_as_int(t2) & 0xFFF;
  const bool need2 = (t1 - t2) < 0.25f;   // wave-uniform

  const float4* qp = (const float4*)(q + (size_t)qrow * CD);
  const float4* p1 = (const float4*)(items + (size_t)c1i * CD);
  float4 qa = qp[lane * 2], qb = qp[lane * 2 + 1];
  float4 xa = p1[lane * 2], xb = p1[lane * 2 + 1];

  float d1 = qa.x * xa.x + qa.y * xa.y + qa.z * xa.z + qa.w * xa.w +
             qb.x * xb.x + qb.y * xb.y + qb.z * xb.z + qb.w * xb.w;
  float qq = qa.x * qa.x + qa.y * qa.y + qa.z * qa.z + qa.w * qa.w +
             qb.x * qb.x + qb.y * qb.y + qb.z * qb.z + qb.w * qb.w;
  float i1 = xa.x * xa.x + xa.y * xa.y + xa.z * xa.z + xa.w * xa.w +
             xb.x * xb.x + xb.y * xb.y + xb.z * xb.z + xb.w * xb.w;

#pragma unroll
  for (int m = 1; m < 64; m <<= 1) {
    d1 += __shfl_xor(d1, m, 64);
    qq += __shfl_xor(qq, m, 64);
    i1 += __shfl_xor(i1, m, 64);
  }

  float d = d1, nn = i1;
  if (need2) {
    const float4* p2 = (const float4*)(items + (size_t)c2i * CD);
    float4 ya = p2[lane * 2], yb = p2[lane * 2 + 1];
    float d2 = qa.x * ya.x + qa.y * ya.y + qa.z * ya.z + qa.w * ya.w +
               qb.x * yb.x + qb.y * yb.y + qb.z * yb.z + qb.w * yb.w;
    float i2 = ya.x * ya.x + ya.y * ya.y + ya.z * ya.z + ya.w * ya.w +
               yb.x * yb.x + yb.y * yb.y + yb.z * yb.z + yb.w * yb.w;
#pragma unroll
    for (int m = 1; m < 64; m <<= 1) {
      d2 += __shfl_xor(d2, m, 64);
      i2 += __shfl_xor(i2, m, 64);
    }
    const bool use2 = (d2 > d1) || (d2 == d1 && c2i < c1i);
    d  = use2 ? d2 : d1;
    nn = use2 ? i2 : i1;
  }

  if (lane == 0) {
    float nq = fmaxf(sqrtf(qq), 1e-12f);
    float np = fmaxf(sqrtf(nn), 1e-12f);
    out[qrow] = -(d / (nq * np));
  }
}

// ---------------------------------------------------------------------------
extern "C" void kernel_launch(void* const* d_in, const int* in_sizes, int n_in,
                              void* d_out, int out_size, void* d_ws,
                              size_t ws_size, hipStream_t stream) {
  const float* q  = (const float*)d_in[0];
  const float* it = (const float*)d_in[1];
  char* ws = (char*)d_ws;
  float* out = (float*)d_out;

  const int IC = MI * CD / 8;
  convert_kernel<<<(IC + 255) / 256, 256, 0, stream>>>(it, ws);
  dim3 grid(TQ / BM, NIS);
  score_kernel<<<grid, 256, 0, stream>>>(q, ws);
  rescue_kernel<<<TQ / 4, 256, 0, stream>>>(q, it, ws, out);
}

// Round 15
// 164.345 us; speedup vs baseline: 1.2894x; 1.2894x over previous
//
#include <hip/hip_runtime.h>

// ---------------------------------------------------------------------------
// NearestSim: out[t] = -cos(q_t, items[argmax_j q_t . items_j])
// T=16384, M=4096, C=512, fp32 in/out.
// R26 = R24 verbatim (revert of R25's reg-staged Q fusion, which spilled:
//       16 in-flight fp32 float4 pairs + 128 live acc > 256 unified regs ->
//       WRITE 99MB, score 132us). R24 is the session best:
//       score 81.6us steady / 168.6us total, WRITE 10.8MB, MfmaUtil 35%.
//  R24 structure: 128q-per-wave tile (8x4 MFMAs of 16x16x32, 128 acc),
//  2-phase K=256 staging via global_load_lds (register-free), depth-2 B
//  rotation, counted prologue barrier, setprio, med3/ds_swizzle epilogue,
//  gap-gated exact-fp32 rescue.
// ---------------------------------------------------------------------------

#define TQ 16384
#define MI 4096
#define CD 512
#define NIS 16          // item splits; block covers 256 items
#define BM 128          // block query rows (= wave q-rows)

typedef _Float16 half8   __attribute__((ext_vector_type(8)));
typedef _Float16 half4_t __attribute__((ext_vector_type(4)));
typedef float    float4t __attribute__((ext_vector_type(4)));

// workspace layout (bytes)
#define QH_OFF   (0u)
#define QH_BYTES ((unsigned)TQ * CD * 2u)          // 16 MB fp16 queries (row-major)
#define IH_OFF   (QH_OFF + QH_BYTES)
#define IH_BYTES ((unsigned)MI * CD * 2u)          // 4 MB fp16 items (fragment order)
#define PART_OFF (IH_OFF + IH_BYTES)
#define PART_BYTES ((unsigned)TQ * 64u * 8u)       // 8 MB: 64 float2 / query
// total 28 MB

__device__ __forceinline__ void lds_load16(const void* g, void* l) {
  __builtin_amdgcn_global_load_lds(
      (const __attribute__((address_space(1))) void*)g,
      (__attribute__((address_space(3))) void*)l, 16, 0, 0);
}

template <int SWZ>
__device__ __forceinline__ float swz_f(float x) {
  return __int_as_float(__builtin_amdgcn_ds_swizzle(__float_as_int(x), SWZ));
}

// ---------------- kernel 1: fp32 -> fp16 conversion -------------------------
// Q: row-major half4 copy. Items: fragment order (chunk = (tile16*16+kk)*64
// + lane; lane = quad*16+l15 holds row tile16*16+l15, cols kk*32+quad*8..+8).
__global__ __launch_bounds__(256) void convert_kernel(
    const float* __restrict__ q, const float* __restrict__ it,
    char* __restrict__ ws) {
  const int idx = blockIdx.x * 256 + threadIdx.x;
  const int QV = TQ * CD / 4;   // Q: one half4 per thread
  const int IC = MI * CD / 8;   // items: one 16B chunk per thread
  if (idx < QV) {
    float4 v = ((const float4*)q)[idx];
    half4_t h = {(_Float16)v.x, (_Float16)v.y, (_Float16)v.z, (_Float16)v.w};
    ((half4_t*)(ws + QH_OFF))[idx] = h;
  }
  const int ic = idx - QV;
  if (ic >= 0 && ic < IC) {
    const int tile = ic >> 10;          // 1024 chunks per 16-row tile
    const int rem  = ic & 1023;
    const int kk   = rem >> 6;
    const int lane = rem & 63;
    const int row  = tile * 16 + (lane & 15);
    const int col  = kk * 32 + (lane >> 4) * 8;
    const float4* s = (const float4*)(it + (size_t)row * CD + col);
    float4 v0 = s[0], v1 = s[1];
    half8 h = {(_Float16)v0.x, (_Float16)v0.y, (_Float16)v0.z, (_Float16)v0.w,
               (_Float16)v1.x, (_Float16)v1.y, (_Float16)v1.z, (_Float16)v1.w};
    *(half8*)(ws + IH_OFF + (size_t)ic * 16) = h;
  }
}

// ---------------- kernel 2: 128q-per-wave fused GEMM + packed top-2 ---------
// grid (TQ/128, NIS), block 256 = 4 waves; wave tile 128q x 64i (8x4 MFMAs
// of 16x16x32, 128 acc). A image: 2 phases of K=256, 128 rows x 512B = 64KB.
// B direct global, depth-2 rotation (bC/bN/bN2), 4 loads/kstep.
// LDS image (per phase): row r (0..127) at r*512; 32 chunks of 16B;
// phys chunk = logical c ^ (r&15)  -> a-frag b128 reads conflict-free.
// Staging (16 instr): instr j, thread t -> dest = j*4096 + t*16
//   row = j*8 + (t>>5), phys chunk = t&31,
//   logical c = (t&31) ^ (row&15) = (t&31) ^ (t>>5) ^ (8*(j&1)).
__global__ __launch_bounds__(256, 2) void score_kernel(char* __restrict__ ws) {
  __shared__ __align__(16) char sA[65536];  // 64 KB, re-staged per phase

  const int tid  = threadIdx.x;
  const int lane = tid & 63;
  const int wave = tid >> 6;       // 0..3 (item group)
  const int quad = lane >> 4;
  const int l15  = lane & 15;
  const int qtile = blockIdx.x;    // 0..127; XCD = qtile%8
  const int isplit = blockIdx.y;

  // staging source (two variants by j&1): + (j>>1)*16384 + phase*512
  const char* Qbase = ws + QH_OFF + (size_t)qtile * BM * 1024;
  const char* gA = Qbase + (tid >> 5) * 1024 +
                   (((tid & 31) ^ (tid >> 5)) << 4);
  const char* gB = Qbase + 8192 + (tid >> 5) * 1024 +
                   (((tid & 31) ^ 8 ^ (tid >> 5)) << 4);
  const int ldst = tid * 16;  // + j*4096

  // B stream: tile(ni) = isplit*16 + wave*4 + ni
  const char* Ibase = ws + IH_OFF;
  int bOff[4];
#pragma unroll
  for (int ni = 0; ni < 4; ++ni)
    bOff[ni] = ((isplit * 16 + wave * 4 + ni) << 14) + lane * 16;

  // A fragment: byte = mi*8192 + l15*512 + (((kl*4+quad) ^ l15) << 4)
  const int aRow = l15 * 512;

  float4t acc[8][4];
#pragma unroll
  for (int mi = 0; mi < 8; ++mi)
#pragma unroll
    for (int ni = 0; ni < 4; ++ni) acc[mi][ni] = (float4t){0.f, 0.f, 0.f, 0.f};

  half8 aC[8], bC[4], bN[4], bN2[4];

#define STAGE(ph)                                                         \
  {                                                                       \
    _Pragma("unroll") for (int j = 0; j < 16; ++j)                        \
      lds_load16(((j & 1) ? gB : gA) + (j >> 1) * 16384 + (ph) * 512,     \
                 sA + j * 4096 + ldst);                                   \
  }

  STAGE(0);
  __builtin_amdgcn_sched_barrier(0);  // pin: B prologue issues AFTER staging

  // B prologue: k0 -> bC, k1 -> bN (8 loads, stay in flight)
#pragma unroll
  for (int ni = 0; ni < 4; ++ni) bC[ni] = *(const half8*)(Ibase + bOff[ni]);
#pragma unroll
  for (int ni = 0; ni < 4; ++ni)
    bN[ni] = *(const half8*)(Ibase + bOff[ni] + 1024);

  // 24 outstanding; vmcnt(8) drains the 16 oldest = all stage loads,
  // leaves the 8 B-prologue loads in flight.
  asm volatile("s_waitcnt vmcnt(8)\n\ts_barrier" ::: "memory");

#define KPHASE(ph)                                                        \
  {                                                                       \
    _Pragma("unroll") for (int kl = 0; kl < 8; ++kl) {                    \
      const int kkg = (ph) * 8 + kl;                                      \
      if (kkg + 2 < 16) {  /* depth-2 B prefetch */                       \
        _Pragma("unroll") for (int ni = 0; ni < 4; ++ni)                  \
          bN2[ni] = *(const half8*)(Ibase + bOff[ni] + 2048);             \
      }                                                                   \
      {  /* a-frags for this kstep (no prefetch; TLP covers ds latency) */\
        const int c = (((kl << 2) + quad) ^ l15) << 4;                    \
        _Pragma("unroll") for (int mi = 0; mi < 8; ++mi)                  \
          aC[mi] = *(const half8*)(sA + mi * 8192 + aRow + c);            \
      }                                                                   \
      __builtin_amdgcn_s_setprio(1);                                      \
      _Pragma("unroll") for (int mi = 0; mi < 8; ++mi)                    \
        _Pragma("unroll") for (int ni = 0; ni < 4; ++ni)                  \
          acc[mi][ni] = __builtin_amdgcn_mfma_f32_16x16x32_f16(           \
              aC[mi], bC[ni], acc[mi][ni], 0, 0, 0);                      \
      __builtin_amdgcn_s_setprio(0);                                      \
      _Pragma("unroll") for (int x = 0; x < 4; ++x) bC[x] = bN[x];        \
      if (kkg + 2 < 16) {                                                 \
        _Pragma("unroll") for (int x = 0; x < 4; ++x) bN[x] = bN2[x];     \
      }                                                                   \
      _Pragma("unroll") for (int ni = 0; ni < 4; ++ni) bOff[ni] += 1024;  \
    }                                                                     \
  }

  KPHASE(0);
  __syncthreads();   // all phase-0 a-reads done (drains k8/k9 B: needed now)
  STAGE(1);
  __syncthreads();   // staged image visible
  KPHASE(1);

#undef KPHASE
#undef STAGE

  // ---- epilogue: packed (score | 12-bit global idx) top-2 per query row ----
  // C row = mi*16 + quad*4 + r, col = l15.
  // item = isplit*256 + wave*64 + ni*16 + l15.
  float t1[32], t2[32];

  const int locBase = isplit * 256 + wave * 64 + l15;
#pragma unroll
  for (int ni = 0; ni < 4; ++ni) {
    const int loc = locBase + ni * 16;
#pragma unroll
    for (int mi = 0; mi < 8; ++mi) {
#pragma unroll
      for (int r = 0; r < 4; ++r) {
        const int s = mi * 4 + r;
        const float pv = __int_as_float(
            (__float_as_int(acc[mi][ni][r]) & 0xFFFFF000) | loc);
        if (ni == 0) {
          t1[s] = pv;
          t2[s] = -1e30f;
        } else {
          t2[s] = __builtin_amdgcn_fmed3f(pv, t1[s], t2[s]);
          t1[s] = fmaxf(t1[s], pv);
        }
      }
    }
  }

  // 4-step butterfly across the 16-lane l15 group via ds_swizzle xor
  // patterns (BitMode: offset = (xor<<10)|0x1F). Disjoint partner sets:
  //   t2' = med3(t1, o1, max(t2, o2)) = max(min(t1,o1), max(t2,o2)).
#define BSTEP(SWZ)                                                       \
  {                                                                      \
    _Pragma("unroll") for (int s = 0; s < 32; ++s) {                     \
      const float o1 = swz_f<SWZ>(t1[s]);                                \
      const float o2 = swz_f<SWZ>(t2[s]);                                \
      t2[s] = __builtin_amdgcn_fmed3f(t1[s], o1, fmaxf(t2[s], o2));      \
      t1[s] = fmaxf(t1[s], o1);                                          \
    }                                                                    \
  }
  BSTEP(0x041F)   // xor 1
  BSTEP(0x081F)   // xor 2
  BSTEP(0x101F)   // xor 4
  BSTEP(0x201F)   // xor 8
#undef BSTEP

  // writer: l15 == 0; entry = isplit*4 + wave. 64 entries per query.
  if (l15 == 0) {
    float2* part = (float2*)(ws + PART_OFF);
    const int e = isplit * 4 + wave;
#pragma unroll
    for (int s = 0; s < 32; ++s) {
      const int qrow = qtile * BM + (s >> 2) * 16 + quad * 4 + (s & 3);
      part[(size_t)qrow * 64 + e] = make_float2(t1[s], t2[s]);
    }
  }
}

// ---------------- kernel 3: merge partials + exact fp32 rescue --------------
// one wave per query: 64 packed entries (1/lane) -> global fp16 top-2.
// If the packed gap exceeds 0.25 (>>5 sigma of fp16+quant score error),
// candidate 1 is certainly the true argmax: skip the 2nd gather entirely
// (wave-uniform branch). Otherwise exact fp32 re-score of both.
__global__ __launch_bounds__(256) void rescue_kernel(
    const float* __restrict__ q, const float* __restrict__ items,
    const char* __restrict__ ws, float* __restrict__ out) {
  const int wave = threadIdx.x >> 6;
  const int lane = threadIdx.x & 63;
  const int qrow = blockIdx.x * 4 + wave;

  const float2* part = (const float2*)(ws + PART_OFF);
  float2 ent = part[(size_t)qrow * 64 + lane];  // coalesced 512B burst
  float t1 = ent.x, t2 = ent.y;

#pragma unroll
  for (int m = 1; m < 64; m <<= 1) {
    const float o1 = __shfl_xor(t1, m, 64);
    const float o2 = __shfl_xor(t2, m, 64);
    const float mn = fminf(t1, o1);
    t1 = fmaxf(t1, o1);
    t2 = fmaxf(fmaxf(t2, o2), mn);
  }
  const int c1i = __float_as_int(t1) & 0xFFF;
  const int c2i = __float_as_int(t2) & 0xFFF;
  const bool need2 = (t1 - t2) < 0.25f;   // wave-uniform

  const float4* qp = (const float4*)(q + (size_t)qrow * CD);
  const float4* p1 = (const float4*)(items + (size_t)c1i * CD);
  float4 qa = qp[lane * 2], qb = qp[lane * 2 + 1];
  float4 xa = p1[lane * 2], xb = p1[lane * 2 + 1];

  float d1 = qa.x * xa.x + qa.y * xa.y + qa.z * xa.z + qa.w * xa.w +
             qb.x * xb.x + qb.y * xb.y + qb.z * xb.z + qb.w * xb.w;
  float qq = qa.x * qa.x + qa.y * qa.y + qa.z * qa.z + qa.w * qa.w +
             qb.x * qb.x + qb.y * qb.y + qb.z * qb.z + qb.w * qb.w;
  float i1 = xa.x * xa.x + xa.y * xa.y + xa.z * xa.z + xa.w * xa.w +
             xb.x * xb.x + xb.y * xb.y + xb.z * xb.z + xb.w * xb.w;

#pragma unroll
  for (int m = 1; m < 64; m <<= 1) {
    d1 += __shfl_xor(d1, m, 64);
    qq += __shfl_xor(qq, m, 64);
    i1 += __shfl_xor(i1, m, 64);
  }

  float d = d1, nn = i1;
  if (need2) {
    const float4* p2 = (const float4*)(items + (size_t)c2i * CD);
    float4 ya = p2[lane * 2], yb = p2[lane * 2 + 1];
    float d2 = qa.x * ya.x + qa.y * ya.y + qa.z * ya.z + qa.w * ya.w +
               qb.x * yb.x + qb.y * yb.y + qb.z * yb.z + qb.w * yb.w;
    float i2 = ya.x * ya.x + ya.y * ya.y + ya.z * ya.z + ya.w * ya.w +
               yb.x * yb.x + yb.y * yb.y + yb.z * yb.z + yb.w * yb.w;
#pragma unroll
    for (int m = 1; m < 64; m <<= 1) {
      d2 += __shfl_xor(d2, m, 64);
      i2 += __shfl_xor(i2, m, 64);
    }
    const bool use2 = (d2 > d1) || (d2 == d1 && c2i < c1i);
    d  = use2 ? d2 : d1;
    nn = use2 ? i2 : i1;
  }

  if (lane == 0) {
    float nq = fmaxf(sqrtf(qq), 1e-12f);
    float np = fmaxf(sqrtf(nn), 1e-12f);
    out[qrow] = -(d / (nq * np));
  }
}

// ---------------------------------------------------------------------------
extern "C" void kernel_launch(void* const* d_in, const int* in_sizes, int n_in,
                              void* d_out, int out_size, void* d_ws,
                              size_t ws_size, hipStream_t stream) {
  const float* q  = (const float*)d_in[0];
  const float* it = (const float*)d_in[1];
  char* ws = (char*)d_ws;
  float* out = (float*)d_out;

  const int total = TQ * CD / 4 + MI * CD / 8;
  convert_kernel<<<(total + 255) / 256, 256, 0, stream>>>(q, it, ws);
  dim3 grid(TQ / BM, NIS);
  score_kernel<<<grid, 256, 0, stream>>>(ws);
  rescue_kernel<<<TQ / 4, 256, 0, stream>>>(q, it, ws, out);
}